// Round 4
// baseline (384.842 us; speedup 1.0000x reference)
//
#include <hip/hip_runtime.h>
#include <hip/hip_bf16.h>

typedef __attribute__((ext_vector_type(8))) short bf16x8;
typedef __attribute__((ext_vector_type(4))) float f32x4;

typedef __attribute__((address_space(1))) void as1_void;
typedef __attribute__((address_space(3))) void as3_void;

__device__ __forceinline__ void gload16(const void* g, void* l) {
  __builtin_amdgcn_global_load_lds((as1_void*)(void*)g, (as3_void*)l, 16, 0, 0);
}

__device__ __forceinline__ f32x4 mfma16(bf16x8 a, bf16x8 b, f32x4 c) {
  return __builtin_amdgcn_mfma_f32_16x16x32_bf16(a, b, c, 0, 0, 0);
}

// ---------------- cast fp32 -> bf16, 4 elems/thread ----------------
__global__ __launch_bounds__(256) void castf2b(const float* __restrict__ s,
                                               __hip_bfloat16* __restrict__ d, int n) {
  int i = (blockIdx.x * 256 + threadIdx.x) * 4;
  if (i >= n) return;
  float4 f = *reinterpret_cast<const float4*>(s + i);
  union { __hip_bfloat16 h[4]; uint2 u; } cv;
  cv.h[0] = __float2bfloat16(f.x);
  cv.h[1] = __float2bfloat16(f.y);
  cv.h[2] = __float2bfloat16(f.z);
  cv.h[3] = __float2bfloat16(f.w);
  *reinterpret_cast<uint2*>(d + i) = cv.u;
}

// ---------------- pack int32 mask -> bitmask (1 bit per element) ----------------
__global__ __launch_bounds__(256) void mask_pack(const int* __restrict__ m,
                                                 unsigned long long* __restrict__ bits) {
  int g = blockIdx.x * 256 + threadIdx.x;
  unsigned long long bal = __ballot(m[g] != 0);
  if ((threadIdx.x & 63) == 0) bits[g >> 6] = bal;
}

// ---------------- V transpose: [bh][2048][64] -> [bh][64][2048] ----------------
__global__ __launch_bounds__(256) void vtrans(const __hip_bfloat16* __restrict__ v,
                                              __hip_bfloat16* __restrict__ vt) {
  int bh = blockIdx.x >> 5;
  int s0 = (blockIdx.x & 31) * 64;
  __shared__ __align__(16) __hip_bfloat16 tile[64][72];
  const __hip_bfloat16* src = v + ((size_t)bh * 2048 + s0) * 64;
  int t = threadIdx.x;
#pragma unroll
  for (int i = 0; i < 2; i++) {
    int c = t + i * 256;
    int r = c >> 3, c8 = (c & 7) * 8;
    *reinterpret_cast<uint4*>(&tile[r][c8]) =
        *reinterpret_cast<const uint4*>(src + (size_t)r * 64 + c8);
  }
  __syncthreads();
  __hip_bfloat16* dst = vt + (size_t)bh * 64 * 2048 + s0;
#pragma unroll
  for (int i = 0; i < 2; i++) {
    int c = t + i * 256;
    int d = c >> 3, s8 = (c & 7) * 8;
    __hip_bfloat16 tmp[8] __attribute__((aligned(16)));
#pragma unroll
    for (int j = 0; j < 8; j++) tmp[j] = tile[s8 + j][d];
    *reinterpret_cast<uint4*>(dst + (size_t)d * 2048 + s8) =
        *reinterpret_cast<const uint4*>(tmp);
  }
}

// ---------------- GEMM C = A * B^T (+bias), 128x128x64 tile, 4 waves ----------------
// MODE 0: A=x_bf16[4096,1024], B=Wqkv[3072,1024]; epilogue scatters q (x1/8), k, v
//         into [bh][s][64] bf16 layouts with per-segment bias.
// MODE 1: A=ctx[4096,1024], B=Wo[1024,1024]; epilogue writes FP32 row-major + bias
//         (d_out is float* — reference output dtype is float32).
template <int MODE>
__global__ __launch_bounds__(256) void gemm_bt(
    const __hip_bfloat16* __restrict__ A, const __hip_bfloat16* __restrict__ Bw,
    const float* __restrict__ bias0, const float* __restrict__ bias1,
    const float* __restrict__ bias2, __hip_bfloat16* __restrict__ out0,
    __hip_bfloat16* __restrict__ out1, __hip_bfloat16* __restrict__ out2,
    float* __restrict__ foutp, int M, int N, int K) {
  __shared__ __align__(16) __hip_bfloat16 Alds[128 * 64];
  __shared__ __align__(16) __hip_bfloat16 Blds[128 * 64];
  const int t = threadIdx.x;
  const int lane = t & 63;
  const int w = t >> 6;
  const int wr = w >> 1, wc = w & 1;
  const int l15 = lane & 15, lhi = lane >> 4;
  const int Nt = N >> 7;
  const int bm = (int)blockIdx.x / Nt, bn = (int)blockIdx.x % Nt;
  const int m0 = bm * 128, n0 = bn * 128;

  const f32x4 fzero = {0.f, 0.f, 0.f, 0.f};
  f32x4 acc[4][4];
#pragma unroll
  for (int mi = 0; mi < 4; mi++)
#pragma unroll
    for (int ni = 0; ni < 4; ni++) acc[mi][ni] = fzero;

  for (int k0 = 0; k0 < K; k0 += 64) {
#pragma unroll
    for (int i = 0; i < 4; i++) {
      int c = t + i * 256;           // 16B chunk id, 1024 per tile
      int r = c >> 3, c8 = (c & 7) * 8;
      gload16(A + (size_t)(m0 + r) * K + k0 + c8, (char*)Alds + c * 16);
      gload16(Bw + (size_t)(n0 + r) * K + k0 + c8, (char*)Blds + c * 16);
    }
    __syncthreads();
#pragma unroll
    for (int kk = 0; kk < 2; kk++) {
      bf16x8 af[4], bfr[4];
#pragma unroll
      for (int mi = 0; mi < 4; mi++)
        af[mi] = *reinterpret_cast<const bf16x8*>(
            &Alds[(wr * 64 + mi * 16 + l15) * 64 + kk * 32 + lhi * 8]);
#pragma unroll
      for (int ni = 0; ni < 4; ni++)
        bfr[ni] = *reinterpret_cast<const bf16x8*>(
            &Blds[(wc * 64 + ni * 16 + l15) * 64 + kk * 32 + lhi * 8]);
#pragma unroll
      for (int mi = 0; mi < 4; mi++)
#pragma unroll
        for (int ni = 0; ni < 4; ni++)
          acc[mi][ni] = mfma16(af[mi], bfr[ni], acc[mi][ni]);
    }
    __syncthreads();
  }

#pragma unroll
  for (int mi = 0; mi < 4; mi++) {
#pragma unroll
    for (int ni = 0; ni < 4; ni++) {
#pragma unroll
      for (int r = 0; r < 4; r++) {
        int gr = m0 + wr * 64 + mi * 16 + lhi * 4 + r;
        int gc = n0 + wc * 64 + ni * 16 + l15;
        float v = acc[mi][ni][r];
        if (MODE == 0) {
          int seg = gc >> 10, e = gc & 1023, h = e >> 6, d = e & 63;
          int b = gr >> 11, s = gr & 2047;
          size_t idx = (((size_t)(b * 16 + h)) * 2048 + s) * 64 + d;
          if (seg == 0)
            out0[idx] = __float2bfloat16((v + bias0[e]) * 0.125f);
          else if (seg == 1)
            out1[idx] = __float2bfloat16(v + bias1[e]);
          else
            out2[idx] = __float2bfloat16(v + bias2[e]);
        } else {
          foutp[(size_t)gr * N + gc] = v + bias0[gc];
        }
      }
    }
  }
}

// ---------------- Flash attention ----------------
// Q,K: [bh][2048][64] (Q pre-scaled by 1/8); VT: [bh][64][2048];
// mb: bitmask [b][2048][32] u64; ctx out: [b][s][h*64+d] bf16.
__global__ __launch_bounds__(256) void attn(
    const __hip_bfloat16* __restrict__ Q, const __hip_bfloat16* __restrict__ Kk,
    const __hip_bfloat16* __restrict__ VT,
    const unsigned long long* __restrict__ mb, __hip_bfloat16* __restrict__ ctx) {
  const int bx = blockIdx.x;
  const int bh = bx >> 5, qb = bx & 31;
  const int b = bh >> 4, h = bh & 15;
  const int t = threadIdx.x, lane = t & 63, w = t >> 6;
  const int l15 = lane & 15, lhi = lane >> 4;
  const int q0 = qb * 64 + w * 16;  // wave's q base within this head

  __shared__ __align__(16) __hip_bfloat16 Ks[64 * 64];
  __shared__ __align__(16) __hip_bfloat16 Vs[64 * 64];  // [d][kv]
  __shared__ __align__(16) __hip_bfloat16 Ps[4][16 * 64];

  bf16x8 qf[2];
  {
    const size_t qbase = ((size_t)bh * 2048 + q0 + l15) * 64;
    qf[0] = *reinterpret_cast<const bf16x8*>(Q + qbase + lhi * 8);
    qf[1] = *reinterpret_cast<const bf16x8*>(Q + qbase + 32 + lhi * 8);
  }

  const f32x4 fzero = {0.f, 0.f, 0.f, 0.f};
  f32x4 o[4];
  float mrun[4], lrun[4];
#pragma unroll
  for (int r = 0; r < 4; r++) { mrun[r] = -1e30f; lrun[r] = 0.f; }
#pragma unroll
  for (int dt = 0; dt < 4; dt++) o[dt] = fzero;

  const __hip_bfloat16* Kbase = Kk + (size_t)bh * 2048 * 64;
  const __hip_bfloat16* Vbase = VT + (size_t)bh * 64 * 2048;

  for (int kv0 = 0; kv0 < 2048; kv0 += 64) {
#pragma unroll
    for (int i = 0; i < 2; i++) {
      int c = t + i * 256;
      gload16(Kbase + (size_t)kv0 * 64 + c * 8, (char*)Ks + c * 16);
      gload16(Vbase + (size_t)(c >> 3) * 2048 + kv0 + (c & 7) * 8,
              (char*)Vs + c * 16);
    }
    __syncthreads();

    f32x4 s[4];
#pragma unroll
    for (int ct = 0; ct < 4; ct++) s[ct] = fzero;
#pragma unroll
    for (int ct = 0; ct < 4; ct++) {
#pragma unroll
      for (int kk = 0; kk < 2; kk++) {
        bf16x8 kf = *reinterpret_cast<const bf16x8*>(
            &Ks[(ct * 16 + l15) * 64 + kk * 32 + lhi * 8]);
        s[ct] = mfma16(qf[kk], kf, s[ct]);
      }
    }
    // mask
    unsigned long long mbits[4];
#pragma unroll
    for (int r = 0; r < 4; r++)
      mbits[r] = mb[((size_t)b * 2048 + q0 + lhi * 4 + r) * 32 + (kv0 >> 6)];
#pragma unroll
    for (int ct = 0; ct < 4; ct++)
#pragma unroll
      for (int r = 0; r < 4; r++)
        if (!((mbits[r] >> (ct * 16 + l15)) & 1ull)) s[ct][r] = -1e9f;

    // online softmax
    float rowm[4];
#pragma unroll
    for (int r = 0; r < 4; r++)
      rowm[r] = fmaxf(fmaxf(s[0][r], s[1][r]), fmaxf(s[2][r], s[3][r]));
#pragma unroll
    for (int off = 1; off < 16; off <<= 1)
#pragma unroll
      for (int r = 0; r < 4; r++)
        rowm[r] = fmaxf(rowm[r], __shfl_xor(rowm[r], off));
    float scl[4];
#pragma unroll
    for (int r = 0; r < 4; r++) {
      float nm = fmaxf(mrun[r], rowm[r]);
      scl[r] = __expf(mrun[r] - nm);
      mrun[r] = nm;
    }
    float pv[4][4], rsum[4];
#pragma unroll
    for (int r = 0; r < 4; r++) rsum[r] = 0.f;
#pragma unroll
    for (int ct = 0; ct < 4; ct++)
#pragma unroll
      for (int r = 0; r < 4; r++) {
        pv[ct][r] = __expf(s[ct][r] - mrun[r]);
        rsum[r] += pv[ct][r];
      }
#pragma unroll
    for (int off = 1; off < 16; off <<= 1)
#pragma unroll
      for (int r = 0; r < 4; r++) rsum[r] += __shfl_xor(rsum[r], off);
#pragma unroll
    for (int r = 0; r < 4; r++) lrun[r] = lrun[r] * scl[r] + rsum[r];
#pragma unroll
    for (int dt = 0; dt < 4; dt++)
#pragma unroll
      for (int r = 0; r < 4; r++) o[dt][r] *= scl[r];

    // P -> LDS (bf16) for PV A-operand
#pragma unroll
    for (int ct = 0; ct < 4; ct++)
#pragma unroll
      for (int r = 0; r < 4; r++)
        Ps[w][(lhi * 4 + r) * 64 + ct * 16 + l15] = __float2bfloat16(pv[ct][r]);
    __syncthreads();

#pragma unroll
    for (int kk = 0; kk < 2; kk++) {
      bf16x8 pf = *reinterpret_cast<const bf16x8*>(
          &Ps[w][l15 * 64 + kk * 32 + lhi * 8]);
#pragma unroll
      for (int dt = 0; dt < 4; dt++) {
        bf16x8 vf = *reinterpret_cast<const bf16x8*>(
            &Vs[(dt * 16 + l15) * 64 + kk * 32 + lhi * 8]);
        o[dt] = mfma16(pf, vf, o[dt]);
      }
    }
    __syncthreads();
  }

#pragma unroll
  for (int dt = 0; dt < 4; dt++)
#pragma unroll
    for (int r = 0; r < 4; r++) {
      int srow = q0 + lhi * 4 + r;
      float val = o[dt][r] / lrun[r];
      ctx[(((size_t)b * 2048 + srow) * 16 + h) * 64 + dt * 16 + l15] =
          __float2bfloat16(val);
    }
}

extern "C" void kernel_launch(void* const* d_in, const int* in_sizes, int n_in,
                              void* d_out, int out_size, void* d_ws,
                              size_t ws_size, hipStream_t stream) {
  const float* x = (const float*)d_in[0];
  const int* mask = (const int*)d_in[1];
  const float* Wq = (const float*)d_in[2];
  const float* bq = (const float*)d_in[3];
  const float* Wk = (const float*)d_in[4];
  const float* bk = (const float*)d_in[5];
  const float* Wv = (const float*)d_in[6];
  const float* bv = (const float*)d_in[7];
  const float* Wo = (const float*)d_in[8];
  const float* bo = (const float*)d_in[9];
  float* out = (float*)d_out;  // reference output dtype is float32
  char* ws = (char*)d_ws;

  // ws layout (bytes)
  __hip_bfloat16* xb   = (__hip_bfloat16*)(ws);              // 8 MiB
  __hip_bfloat16* wqkv = (__hip_bfloat16*)(ws + 8388608);    // 6 MiB
  __hip_bfloat16* wo   = (__hip_bfloat16*)(ws + 14680064);   // 2 MiB
  __hip_bfloat16* qws  = (__hip_bfloat16*)(ws + 16777216);   // 8 MiB
  __hip_bfloat16* kws  = (__hip_bfloat16*)(ws + 25165824);   // 8 MiB
  __hip_bfloat16* vtmp = (__hip_bfloat16*)(ws + 33554432);   // 8 MiB
  __hip_bfloat16* vt   = (__hip_bfloat16*)(ws + 41943040);   // 8 MiB
  __hip_bfloat16* ctx  = (__hip_bfloat16*)(ws + 50331648);   // 8 MiB
  unsigned long long* mbits = (unsigned long long*)(ws + 58720256);  // 1 MiB

  castf2b<<<4096, 256, 0, stream>>>(x, xb, 4194304);
  castf2b<<<1024, 256, 0, stream>>>(Wq, wqkv, 1048576);
  castf2b<<<1024, 256, 0, stream>>>(Wk, wqkv + 1048576, 1048576);
  castf2b<<<1024, 256, 0, stream>>>(Wv, wqkv + 2097152, 1048576);
  castf2b<<<1024, 256, 0, stream>>>(Wo, wo, 1048576);
  mask_pack<<<32768, 256, 0, stream>>>(mask, mbits);

  gemm_bt<0><<<768, 256, 0, stream>>>(xb, wqkv, bq, bk, bv, qws, kws, vtmp,
                                      nullptr, 4096, 3072, 1024);
  vtrans<<<1024, 256, 0, stream>>>(vtmp, vt);
  attn<<<1024, 256, 0, stream>>>(qws, kws, vt, mbits, ctx);
  gemm_bt<1><<<256, 256, 0, stream>>>(ctx, wo, bo, nullptr, nullptr, nullptr,
                                      nullptr, nullptr, out, 4096, 1024, 1024);
}

// Round 8
// 367.227 us; speedup vs baseline: 1.0480x; 1.0480x over previous
//
#include <hip/hip_runtime.h>
#include <hip/hip_bf16.h>

typedef __attribute__((ext_vector_type(8))) short bf16x8;
typedef __attribute__((ext_vector_type(4))) float f32x4;

typedef __attribute__((address_space(1))) void as1_void;
typedef __attribute__((address_space(3))) void as3_void;

__device__ __forceinline__ void gload16(const void* g, void* l) {
  __builtin_amdgcn_global_load_lds((as1_void*)(void*)g, (as3_void*)l, 16, 0, 0);
}

__device__ __forceinline__ f32x4 mfma16(bf16x8 a, bf16x8 b, f32x4 c) {
  return __builtin_amdgcn_mfma_f32_16x16x32_bf16(a, b, c, 0, 0, 0);
}

// ---------------- cast fp32 -> bf16, 4 elems/thread ----------------
__global__ __launch_bounds__(256) void castf2b(const float* __restrict__ s,
                                               __hip_bfloat16* __restrict__ d, int n) {
  int i = (blockIdx.x * 256 + threadIdx.x) * 4;
  if (i >= n) return;
  float4 f = *reinterpret_cast<const float4*>(s + i);
  union { __hip_bfloat16 h[4]; uint2 u; } cv;
  cv.h[0] = __float2bfloat16(f.x);
  cv.h[1] = __float2bfloat16(f.y);
  cv.h[2] = __float2bfloat16(f.z);
  cv.h[3] = __float2bfloat16(f.w);
  *reinterpret_cast<uint2*>(d + i) = cv.u;
}

// ---------------- pack int32 mask -> bitmask (1 bit per element) ----------------
__global__ __launch_bounds__(256) void mask_pack(const int* __restrict__ m,
                                                 unsigned long long* __restrict__ bits) {
  int g = blockIdx.x * 256 + threadIdx.x;
  unsigned long long bal = __ballot(m[g] != 0);
  if ((threadIdx.x & 63) == 0) bits[g >> 6] = bal;
}

// ---------------- V transpose: [bh][2048][64] -> [bh][64][2048] ----------------
__global__ __launch_bounds__(256) void vtrans(const __hip_bfloat16* __restrict__ v,
                                              __hip_bfloat16* __restrict__ vt) {
  int bh = blockIdx.x >> 5;
  int s0 = (blockIdx.x & 31) * 64;
  __shared__ __align__(16) __hip_bfloat16 tile[64][72];
  const __hip_bfloat16* src = v + ((size_t)bh * 2048 + s0) * 64;
  int t = threadIdx.x;
#pragma unroll
  for (int i = 0; i < 2; i++) {
    int c = t + i * 256;
    int r = c >> 3, c8 = (c & 7) * 8;
    *reinterpret_cast<uint4*>(&tile[r][c8]) =
        *reinterpret_cast<const uint4*>(src + (size_t)r * 64 + c8);
  }
  __syncthreads();
  __hip_bfloat16* dst = vt + (size_t)bh * 64 * 2048 + s0;
#pragma unroll
  for (int i = 0; i < 2; i++) {
    int c = t + i * 256;
    int d = c >> 3, s8 = (c & 7) * 8;
    __hip_bfloat16 tmp[8] __attribute__((aligned(16)));
#pragma unroll
    for (int j = 0; j < 8; j++) tmp[j] = tile[s8 + j][d];
    *reinterpret_cast<uint4*>(dst + (size_t)d * 2048 + s8) =
        *reinterpret_cast<const uint4*>(tmp);
  }
}

// ---------------- GEMM C = A * B^T (+bias), 128x128x64 tile, 4 waves ----------------
template <int MODE>
__global__ __launch_bounds__(256) void gemm_bt(
    const __hip_bfloat16* __restrict__ A, const __hip_bfloat16* __restrict__ Bw,
    const float* __restrict__ bias0, const float* __restrict__ bias1,
    const float* __restrict__ bias2, __hip_bfloat16* __restrict__ out0,
    __hip_bfloat16* __restrict__ out1, __hip_bfloat16* __restrict__ out2,
    float* __restrict__ foutp, int M, int N, int K) {
  __shared__ __align__(16) __hip_bfloat16 Alds[128 * 64];
  __shared__ __align__(16) __hip_bfloat16 Blds[128 * 64];
  const int t = threadIdx.x;
  const int lane = t & 63;
  const int w = t >> 6;
  const int wr = w >> 1, wc = w & 1;
  const int l15 = lane & 15, lhi = lane >> 4;
  const int Nt = N >> 7;
  const int bm = (int)blockIdx.x / Nt, bn = (int)blockIdx.x % Nt;
  const int m0 = bm * 128, n0 = bn * 128;

  const f32x4 fzero = {0.f, 0.f, 0.f, 0.f};
  f32x4 acc[4][4];
#pragma unroll
  for (int mi = 0; mi < 4; mi++)
#pragma unroll
    for (int ni = 0; ni < 4; ni++) acc[mi][ni] = fzero;

  for (int k0 = 0; k0 < K; k0 += 64) {
#pragma unroll
    for (int i = 0; i < 4; i++) {
      int c = t + i * 256;           // 16B chunk id, 1024 per tile
      int r = c >> 3, c8 = (c & 7) * 8;
      gload16(A + (size_t)(m0 + r) * K + k0 + c8, (char*)Alds + c * 16);
      gload16(Bw + (size_t)(n0 + r) * K + k0 + c8, (char*)Blds + c * 16);
    }
    __syncthreads();
#pragma unroll
    for (int kk = 0; kk < 2; kk++) {
      bf16x8 af[4], bfr[4];
#pragma unroll
      for (int mi = 0; mi < 4; mi++)
        af[mi] = *reinterpret_cast<const bf16x8*>(
            &Alds[(wr * 64 + mi * 16 + l15) * 64 + kk * 32 + lhi * 8]);
#pragma unroll
      for (int ni = 0; ni < 4; ni++)
        bfr[ni] = *reinterpret_cast<const bf16x8*>(
            &Blds[(wc * 64 + ni * 16 + l15) * 64 + kk * 32 + lhi * 8]);
#pragma unroll
      for (int mi = 0; mi < 4; mi++)
#pragma unroll
        for (int ni = 0; ni < 4; ni++)
          acc[mi][ni] = mfma16(af[mi], bfr[ni], acc[mi][ni]);
    }
    __syncthreads();
  }

#pragma unroll
  for (int mi = 0; mi < 4; mi++) {
#pragma unroll
    for (int ni = 0; ni < 4; ni++) {
#pragma unroll
      for (int r = 0; r < 4; r++) {
        int gr = m0 + wr * 64 + mi * 16 + lhi * 4 + r;
        int gc = n0 + wc * 64 + ni * 16 + l15;
        float v = acc[mi][ni][r];
        if (MODE == 0) {
          int seg = gc >> 10, e = gc & 1023, h = e >> 6, d = e & 63;
          int b = gr >> 11, s = gr & 2047;
          size_t idx = (((size_t)(b * 16 + h)) * 2048 + s) * 64 + d;
          if (seg == 0)
            out0[idx] = __float2bfloat16((v + bias0[e]) * 0.125f);
          else if (seg == 1)
            out1[idx] = __float2bfloat16(v + bias1[e]);
          else
            out2[idx] = __float2bfloat16(v + bias2[e]);
        } else {
          foutp[(size_t)gr * N + gc] = v + bias0[gc];
        }
      }
    }
  }
}

// ---------------- Flash attention (XOR-swizzled LDS, double-buffered KV) ----
// Q,K: [bh][2048][64] (Q pre-scaled by 1/8); VT: [bh][64][2048];
// mb: bitmask [b][2048][32] u64; ctx out: [b][s][h*64+d] bf16.
// LDS tiles are stored with 16B-slot swizzle: slot' = slot ^ (row&7).
// Staging pre-swizzles the GLOBAL source (gload_lds dest must stay linear,
// rule #21); reads apply the same XOR. Involution => bijective.
__global__ __launch_bounds__(256) void attn(
    const __hip_bfloat16* __restrict__ Q, const __hip_bfloat16* __restrict__ Kk,
    const __hip_bfloat16* __restrict__ VT,
    const unsigned long long* __restrict__ mb, __hip_bfloat16* __restrict__ ctx) {
  const int bx = blockIdx.x;
  const int bh = bx >> 5, qb = bx & 31;
  const int b = bh >> 4, h = bh & 15;
  const int t = threadIdx.x, lane = t & 63, w = t >> 6;
  const int l15 = lane & 15, lhi = lane >> 4;
  const int l7 = l15 & 7;
  const int q0 = qb * 64 + w * 16;  // wave's q base within this head

  __shared__ __align__(16) __hip_bfloat16 Ks[2][64 * 64];
  __shared__ __align__(16) __hip_bfloat16 Vs[2][64 * 64];  // [d][kv]
  __shared__ __align__(16) __hip_bfloat16 Ps[4][16 * 64];

  bf16x8 qf[2];
  {
    const size_t qbase = ((size_t)bh * 2048 + q0 + l15) * 64;
    qf[0] = *reinterpret_cast<const bf16x8*>(Q + qbase + lhi * 8);
    qf[1] = *reinterpret_cast<const bf16x8*>(Q + qbase + 32 + lhi * 8);
  }

  const f32x4 fzero = {0.f, 0.f, 0.f, 0.f};
  f32x4 o[4];
  float mrun[4], lrun[4];
#pragma unroll
  for (int r = 0; r < 4; r++) { mrun[r] = -1e30f; lrun[r] = 0.f; }
#pragma unroll
  for (int dt = 0; dt < 4; dt++) o[dt] = fzero;

  const __hip_bfloat16* Kbase = Kk + (size_t)bh * 2048 * 64;
  const __hip_bfloat16* Vbase = VT + (size_t)bh * 64 * 2048;

  // stage KV tile kv0 into buffer buf; global col-slot pre-swizzled
  auto stage = [&](int buf, int kv0) {
#pragma unroll
    for (int i = 0; i < 2; i++) {
      int c = t + i * 256;            // 16B chunk id, 512 per tile
      int r = c >> 3, j = c & 7;      // row, 16B col-slot
      int js = j ^ (r & 7);           // swizzled source slot
      gload16(Kbase + (size_t)(kv0 + r) * 64 + js * 8,
              (char*)&Ks[buf][0] + c * 16);
      gload16(Vbase + (size_t)r * 2048 + kv0 + js * 8,
              (char*)&Vs[buf][0] + c * 16);
    }
  };

  stage(0, 0);
  __syncthreads();

  for (int tkv = 0; tkv < 32; ++tkv) {
    const int cur = tkv & 1;
    const int kv0 = tkv * 64;
    if (tkv < 31) stage(cur ^ 1, kv0 + 64);

    f32x4 s[4];
#pragma unroll
    for (int ct = 0; ct < 4; ct++) s[ct] = fzero;
#pragma unroll
    for (int ct = 0; ct < 4; ct++) {
#pragma unroll
      for (int kk = 0; kk < 2; kk++) {
        bf16x8 kf = *reinterpret_cast<const bf16x8*>(
            &Ks[cur][(ct * 16 + l15) * 64 + ((kk * 4 + lhi) ^ l7) * 8]);
        s[ct] = mfma16(qf[kk], kf, s[ct]);
      }
    }
    // mask
    unsigned long long mbits[4];
#pragma unroll
    for (int r = 0; r < 4; r++)
      mbits[r] = mb[((size_t)b * 2048 + q0 + lhi * 4 + r) * 32 + (kv0 >> 6)];
#pragma unroll
    for (int ct = 0; ct < 4; ct++)
#pragma unroll
      for (int r = 0; r < 4; r++)
        if (!((mbits[r] >> (ct * 16 + l15)) & 1ull)) s[ct][r] = -1e9f;

    // online softmax
    float rowm[4];
#pragma unroll
    for (int r = 0; r < 4; r++)
      rowm[r] = fmaxf(fmaxf(s[0][r], s[1][r]), fmaxf(s[2][r], s[3][r]));
#pragma unroll
    for (int off = 1; off < 16; off <<= 1)
#pragma unroll
      for (int r = 0; r < 4; r++)
        rowm[r] = fmaxf(rowm[r], __shfl_xor(rowm[r], off));
    float scl[4];
#pragma unroll
    for (int r = 0; r < 4; r++) {
      float nm = fmaxf(mrun[r], rowm[r]);
      scl[r] = __expf(mrun[r] - nm);
      mrun[r] = nm;
    }
    float pv[4][4], rsum[4];
#pragma unroll
    for (int r = 0; r < 4; r++) rsum[r] = 0.f;
#pragma unroll
    for (int ct = 0; ct < 4; ct++)
#pragma unroll
      for (int r = 0; r < 4; r++) {
        pv[ct][r] = __expf(s[ct][r] - mrun[r]);
        rsum[r] += pv[ct][r];
      }
#pragma unroll
    for (int off = 1; off < 16; off <<= 1)
#pragma unroll
      for (int r = 0; r < 4; r++) rsum[r] += __shfl_xor(rsum[r], off);
#pragma unroll
    for (int r = 0; r < 4; r++) lrun[r] = lrun[r] * scl[r] + rsum[r];
#pragma unroll
    for (int dt = 0; dt < 4; dt++)
#pragma unroll
      for (int r = 0; r < 4; r++) o[dt][r] *= scl[r];

    // P -> LDS (bf16, swizzled write) for PV A-operand; wave-private buffer
#pragma unroll
    for (int ct = 0; ct < 4; ct++)
#pragma unroll
      for (int r = 0; r < 4; r++) {
        int prow = lhi * 4 + r;
        int pcol = (ct * 16 + l15) ^ ((prow & 7) << 3);
        Ps[w][prow * 64 + pcol] = __float2bfloat16(pv[ct][r]);
      }
    // wave-local: ds_writes must land before this wave's ds_reads of Ps
    asm volatile("s_waitcnt lgkmcnt(0)" ::: "memory");
    __builtin_amdgcn_sched_barrier(0);

#pragma unroll
    for (int kk = 0; kk < 2; kk++) {
      bf16x8 pf = *reinterpret_cast<const bf16x8*>(
          &Ps[w][l15 * 64 + ((kk * 4 + lhi) ^ l7) * 8]);
#pragma unroll
      for (int dt = 0; dt < 4; dt++) {
        bf16x8 vf = *reinterpret_cast<const bf16x8*>(
            &Vs[cur][(dt * 16 + l15) * 64 + ((kk * 4 + lhi) ^ l7) * 8]);
        o[dt] = mfma16(pf, vf, o[dt]);
      }
    }
    // one barrier per KV step: drains staged loads (vmcnt) for next tile and
    // protects buffer cur from being restaged while still in use.
    __syncthreads();
  }

#pragma unroll
  for (int dt = 0; dt < 4; dt++)
#pragma unroll
    for (int r = 0; r < 4; r++) {
      int srow = q0 + lhi * 4 + r;
      float val = o[dt][r] / lrun[r];
      ctx[(((size_t)b * 2048 + srow) * 16 + h) * 64 + dt * 16 + l15] =
          __float2bfloat16(val);
    }
}

extern "C" void kernel_launch(void* const* d_in, const int* in_sizes, int n_in,
                              void* d_out, int out_size, void* d_ws,
                              size_t ws_size, hipStream_t stream) {
  const float* x = (const float*)d_in[0];
  const int* mask = (const int*)d_in[1];
  const float* Wq = (const float*)d_in[2];
  const float* bq = (const float*)d_in[3];
  const float* Wk = (const float*)d_in[4];
  const float* bk = (const float*)d_in[5];
  const float* Wv = (const float*)d_in[6];
  const float* bv = (const float*)d_in[7];
  const float* Wo = (const float*)d_in[8];
  const float* bo = (const float*)d_in[9];
  float* out = (float*)d_out;  // reference output dtype is float32
  char* ws = (char*)d_ws;

  // ws layout (bytes)
  __hip_bfloat16* xb   = (__hip_bfloat16*)(ws);              // 8 MiB
  __hip_bfloat16* wqkv = (__hip_bfloat16*)(ws + 8388608);    // 6 MiB
  __hip_bfloat16* wo   = (__hip_bfloat16*)(ws + 14680064);   // 2 MiB
  __hip_bfloat16* qws  = (__hip_bfloat16*)(ws + 16777216);   // 8 MiB
  __hip_bfloat16* kws  = (__hip_bfloat16*)(ws + 25165824);   // 8 MiB
  __hip_bfloat16* vtmp = (__hip_bfloat16*)(ws + 33554432);   // 8 MiB
  __hip_bfloat16* vt   = (__hip_bfloat16*)(ws + 41943040);   // 8 MiB
  __hip_bfloat16* ctx  = (__hip_bfloat16*)(ws + 50331648);   // 8 MiB
  unsigned long long* mbits = (unsigned long long*)(ws + 58720256);  // 1 MiB

  castf2b<<<4096, 256, 0, stream>>>(x, xb, 4194304);
  castf2b<<<1024, 256, 0, stream>>>(Wq, wqkv, 1048576);
  castf2b<<<1024, 256, 0, stream>>>(Wk, wqkv + 1048576, 1048576);
  castf2b<<<1024, 256, 0, stream>>>(Wv, wqkv + 2097152, 1048576);
  castf2b<<<1024, 256, 0, stream>>>(Wo, wo, 1048576);
  mask_pack<<<32768, 256, 0, stream>>>(mask, mbits);

  gemm_bt<0><<<768, 256, 0, stream>>>(xb, wqkv, bq, bk, bv, qws, kws, vtmp,
                                      nullptr, 4096, 3072, 1024);
  vtrans<<<1024, 256, 0, stream>>>(vtmp, vt);
  attn<<<1024, 256, 0, stream>>>(qws, kws, vt, mbits, ctx);
  gemm_bt<1><<<256, 256, 0, stream>>>(ctx, wo, bo, nullptr, nullptr, nullptr,
                                      nullptr, nullptr, out, 4096, 1024, 1024);
}

// Round 10
// 352.213 us; speedup vs baseline: 1.0926x; 1.0426x over previous
//
#include <hip/hip_runtime.h>
#include <hip/hip_bf16.h>

typedef __attribute__((ext_vector_type(8))) short bf16x8;
typedef __attribute__((ext_vector_type(4))) float f32x4;
typedef __attribute__((ext_vector_type(16))) float f32x16;
typedef unsigned int uint;

typedef __attribute__((address_space(1))) void as1_void;
typedef __attribute__((address_space(3))) void as3_void;

__device__ __forceinline__ void gload16(const void* g, void* l) {
  __builtin_amdgcn_global_load_lds((as1_void*)(void*)g, (as3_void*)l, 16, 0, 0);
}

__device__ __forceinline__ f32x4 mfma16(bf16x8 a, bf16x8 b, f32x4 c) {
  return __builtin_amdgcn_mfma_f32_16x16x32_bf16(a, b, c, 0, 0, 0);
}

__device__ __forceinline__ f32x16 mfma32(bf16x8 a, bf16x8 b, f32x16 c) {
  return __builtin_amdgcn_mfma_f32_32x32x16_bf16(a, b, c, 0, 0, 0);
}

// ---------------- cast fp32 -> bf16, 4 elems/thread ----------------
__global__ __launch_bounds__(256) void castf2b(const float* __restrict__ s,
                                               __hip_bfloat16* __restrict__ d, int n) {
  int i = (blockIdx.x * 256 + threadIdx.x) * 4;
  if (i >= n) return;
  float4 f = *reinterpret_cast<const float4*>(s + i);
  union { __hip_bfloat16 h[4]; uint2 u; } cv;
  cv.h[0] = __float2bfloat16(f.x);
  cv.h[1] = __float2bfloat16(f.y);
  cv.h[2] = __float2bfloat16(f.z);
  cv.h[3] = __float2bfloat16(f.w);
  *reinterpret_cast<uint2*>(d + i) = cv.u;
}

// ---------------- pack int32 mask -> bitmask (1 bit per element) ----------------
__global__ __launch_bounds__(256) void mask_pack(const int* __restrict__ m,
                                                 unsigned long long* __restrict__ bits) {
  int g = blockIdx.x * 256 + threadIdx.x;
  unsigned long long bal = __ballot(m[g] != 0);
  if ((threadIdx.x & 63) == 0) bits[g >> 6] = bal;
}

// ---------------- V transpose: [bh][2048][64] -> [bh][64][2048] ----------------
__global__ __launch_bounds__(256) void vtrans(const __hip_bfloat16* __restrict__ v,
                                              __hip_bfloat16* __restrict__ vt) {
  int bh = blockIdx.x >> 5;
  int s0 = (blockIdx.x & 31) * 64;
  __shared__ __align__(16) __hip_bfloat16 tile[64][72];
  const __hip_bfloat16* src = v + ((size_t)bh * 2048 + s0) * 64;
  int t = threadIdx.x;
#pragma unroll
  for (int i = 0; i < 2; i++) {
    int c = t + i * 256;
    int r = c >> 3, c8 = (c & 7) * 8;
    *reinterpret_cast<uint4*>(&tile[r][c8]) =
        *reinterpret_cast<const uint4*>(src + (size_t)r * 64 + c8);
  }
  __syncthreads();
  __hip_bfloat16* dst = vt + (size_t)bh * 64 * 2048 + s0;
#pragma unroll
  for (int i = 0; i < 2; i++) {
    int c = t + i * 256;
    int d = c >> 3, s8 = (c & 7) * 8;
    __hip_bfloat16 tmp[8] __attribute__((aligned(16)));
#pragma unroll
    for (int j = 0; j < 8; j++) tmp[j] = tile[s8 + j][d];
    *reinterpret_cast<uint4*>(dst + (size_t)d * 2048 + s8) =
        *reinterpret_cast<const uint4*>(tmp);
  }
}

// ---------------- GEMM C = A * B^T (+bias), 128x128x64 tile, 4 waves ----------------
template <int MODE>
__global__ __launch_bounds__(256) void gemm_bt(
    const __hip_bfloat16* __restrict__ A, const __hip_bfloat16* __restrict__ Bw,
    const float* __restrict__ bias0, const float* __restrict__ bias1,
    const float* __restrict__ bias2, __hip_bfloat16* __restrict__ out0,
    __hip_bfloat16* __restrict__ out1, __hip_bfloat16* __restrict__ out2,
    float* __restrict__ foutp, int M, int N, int K) {
  __shared__ __align__(16) __hip_bfloat16 Alds[128 * 64];
  __shared__ __align__(16) __hip_bfloat16 Blds[128 * 64];
  const int t = threadIdx.x;
  const int lane = t & 63;
  const int w = t >> 6;
  const int wr = w >> 1, wc = w & 1;
  const int l15 = lane & 15, lhi = lane >> 4;
  const int Nt = N >> 7;
  const int bm = (int)blockIdx.x / Nt, bn = (int)blockIdx.x % Nt;
  const int m0 = bm * 128, n0 = bn * 128;

  const f32x4 fzero = {0.f, 0.f, 0.f, 0.f};
  f32x4 acc[4][4];
#pragma unroll
  for (int mi = 0; mi < 4; mi++)
#pragma unroll
    for (int ni = 0; ni < 4; ni++) acc[mi][ni] = fzero;

  for (int k0 = 0; k0 < K; k0 += 64) {
#pragma unroll
    for (int i = 0; i < 4; i++) {
      int c = t + i * 256;           // 16B chunk id, 1024 per tile
      int r = c >> 3, c8 = (c & 7) * 8;
      gload16(A + (size_t)(m0 + r) * K + k0 + c8, (char*)Alds + c * 16);
      gload16(Bw + (size_t)(n0 + r) * K + k0 + c8, (char*)Blds + c * 16);
    }
    __syncthreads();
#pragma unroll
    for (int kk = 0; kk < 2; kk++) {
      bf16x8 af[4], bfr[4];
#pragma unroll
      for (int mi = 0; mi < 4; mi++)
        af[mi] = *reinterpret_cast<const bf16x8*>(
            &Alds[(wr * 64 + mi * 16 + l15) * 64 + kk * 32 + lhi * 8]);
#pragma unroll
      for (int ni = 0; ni < 4; ni++)
        bfr[ni] = *reinterpret_cast<const bf16x8*>(
            &Blds[(wc * 64 + ni * 16 + l15) * 64 + kk * 32 + lhi * 8]);
#pragma unroll
      for (int mi = 0; mi < 4; mi++)
#pragma unroll
        for (int ni = 0; ni < 4; ni++)
          acc[mi][ni] = mfma16(af[mi], bfr[ni], acc[mi][ni]);
    }
    __syncthreads();
  }

#pragma unroll
  for (int mi = 0; mi < 4; mi++) {
#pragma unroll
    for (int ni = 0; ni < 4; ni++) {
#pragma unroll
      for (int r = 0; r < 4; r++) {
        int gr = m0 + wr * 64 + mi * 16 + lhi * 4 + r;
        int gc = n0 + wc * 64 + ni * 16 + l15;
        float v = acc[mi][ni][r];
        if (MODE == 0) {
          int seg = gc >> 10, e = gc & 1023, h = e >> 6, d = e & 63;
          int b = gr >> 11, s = gr & 2047;
          size_t idx = (((size_t)(b * 16 + h)) * 2048 + s) * 64 + d;
          if (seg == 0)
            out0[idx] = __float2bfloat16((v + bias0[e]) * 0.125f);
          else if (seg == 1)
            out1[idx] = __float2bfloat16(v + bias1[e]);
          else
            out2[idx] = __float2bfloat16(v + bias2[e]);
        } else {
          foutp[(size_t)gr * N + gc] = v + bias0[gc];
        }
      }
    }
  }
}

// ---------------- Flash attention v2: swapped-QK 32x32 MFMA, no LDS ----------
// Q,K: [bh][2048][64] (Q pre-scaled 1/8); VT: [bh][64][2048]; mb: [b][2048][32]
// u64 bitmask; ctx: [b][s][h*64+d] bf16.
// Swapped QK^T (A=K, B=Q): lane owns q=lane&31; S rows (kv) land per-reg:
// row = (reg&3)+8*(reg>>2)+4*(lane>>5)  [m74/m101 C/D map]. Softmax is
// in-register. Cross-half scalar reductions use __shfl_xor(...,32) — the
// permlane self-swap trick is UNSAFE (two "+v" tied asm operands with the
// same SSA input can share a physreg, making the swap partner-only; round-9
// FAIL 5.8e-3). cvt_pk+permlane on DISTINCT values (T12) is kept. K/V are
// L2-resident -> no LDS, no barriers (lesson #7); reg double-buffer (T14);
// defer-max THR=8 (T13).
__global__ __launch_bounds__(256) void attn2(
    const __hip_bfloat16* __restrict__ Q, const __hip_bfloat16* __restrict__ Kk,
    const __hip_bfloat16* __restrict__ VT,
    const unsigned long long* __restrict__ mb, __hip_bfloat16* __restrict__ ctx) {
  int bx = blockIdx.x;
  int bid = (bx & 7) * 64 + (bx >> 3);  // XCD swizzle, bijective (512 = 8*64)
  int bh = bid >> 4, qc = bid & 15;
  int b = bh >> 4, h = bh & 15;
  int lane = threadIdx.x & 63, w = threadIdx.x >> 6;
  int l31 = lane & 31, lh = lane >> 5, lh4 = lh * 4;
  int q0 = qc * 128 + w * 32;

  const __hip_bfloat16* Qrow = Q + ((size_t)bh * 2048 + q0 + l31) * 64 + lh * 8;
  const __hip_bfloat16* Krow = Kk + ((size_t)bh * 2048 + l31) * 64 + lh * 8;
  const __hip_bfloat16* V0 = VT + ((size_t)bh * 64 + l31) * 2048 + lh * 8;
  const __hip_bfloat16* V1 = V0 + 32 * 2048;
  const unsigned long long* Mrow = mb + ((size_t)b * 2048 + q0 + l31) * 32;

  bf16x8 qf[4];
#pragma unroll
  for (int ck = 0; ck < 4; ck++)
    qf[ck] = *reinterpret_cast<const bf16x8*>(Qrow + ck * 16);

  f32x16 o0 = {}, o1 = {};
  float mrun = -3.0e38f, lrun = 0.f;

  unsigned long long mw = Mrow[0], mwn = 0;
  bool skipm = __all(mw == ~0ull);

  // one 32-kv tile: QK^T -> mask -> online softmax (in-register) -> PV
  auto comp = [&](const bf16x8* kf, const bf16x8* vf, int half) {
    f32x16 s = {};
#pragma unroll
    for (int ck = 0; ck < 4; ck++) s = mfma32(kf[ck], qf[ck], s);
    if (!skipm) {
      uint mh = (uint)(mw >> half) >> lh4;
#pragma unroll
      for (int r = 0; r < 16; r++) {
        int cr = (r & 3) + 8 * (r >> 2);
        if (!((mh >> cr) & 1u)) s[r] = -1e9f;
      }
    }
    float pmax = s[0];
#pragma unroll
    for (int r = 1; r < 16; r++) pmax = fmaxf(pmax, s[r]);
    pmax = fmaxf(pmax, __shfl_xor(pmax, 32));  // cross-half max (safe reduce)
    if (!__all(pmax <= mrun + 8.0f)) {  // defer-max (T13), wave-uniform branch
      float nm = fmaxf(mrun, pmax);
      float scl = __expf(mrun - nm);
      mrun = nm;
      lrun *= scl;
#pragma unroll
      for (int r = 0; r < 16; r++) {  // rare: per-row rescale via shfl
        int cr = (r & 3) + 8 * (r >> 2);
        float sr = __shfl(scl, cr + lh4);
        o0[r] *= sr;
        o1[r] *= sr;
      }
    }
    float p[16];
    float ts = 0.f;
#pragma unroll
    for (int r = 0; r < 16; r++) {
      p[r] = __expf(s[r] - mrun);
      ts += p[r];
    }
    ts += __shfl_xor(ts, 32);  // cross-half sum (safe reduce)
    lrun += ts;
    // P -> bf16 PV A-frag: rows (r&3)+8*(r>>2)+4*lh  ->  kv = lh*8+j per chunk
    uint x0, x1, x2, x3, y0, y1, y2, y3;
    asm("v_cvt_pk_bf16_f32 %0, %1, %2" : "=v"(x0) : "v"(p[0]), "v"(p[1]));
    asm("v_cvt_pk_bf16_f32 %0, %1, %2" : "=v"(y0) : "v"(p[4]), "v"(p[5]));
    asm("v_cvt_pk_bf16_f32 %0, %1, %2" : "=v"(x1) : "v"(p[2]), "v"(p[3]));
    asm("v_cvt_pk_bf16_f32 %0, %1, %2" : "=v"(y1) : "v"(p[6]), "v"(p[7]));
    asm("v_cvt_pk_bf16_f32 %0, %1, %2" : "=v"(x2) : "v"(p[8]), "v"(p[9]));
    asm("v_cvt_pk_bf16_f32 %0, %1, %2" : "=v"(y2) : "v"(p[12]), "v"(p[13]));
    asm("v_cvt_pk_bf16_f32 %0, %1, %2" : "=v"(x3) : "v"(p[10]), "v"(p[11]));
    asm("v_cvt_pk_bf16_f32 %0, %1, %2" : "=v"(y3) : "v"(p[14]), "v"(p[15]));
    asm volatile("v_permlane32_swap_b32 %0, %1" : "+v"(x0), "+v"(y0));
    asm volatile("v_permlane32_swap_b32 %0, %1" : "+v"(x1), "+v"(y1));
    asm volatile("v_permlane32_swap_b32 %0, %1" : "+v"(x2), "+v"(y2));
    asm volatile("v_permlane32_swap_b32 %0, %1" : "+v"(x3), "+v"(y3));
    union { uint u[4]; bf16x8 v8; } pa0, pa1;
    pa0.u[0] = x0; pa0.u[1] = x1; pa0.u[2] = y0; pa0.u[3] = y1;
    pa1.u[0] = x2; pa1.u[1] = x3; pa1.u[2] = y2; pa1.u[3] = y3;
    o0 = mfma32(pa0.v8, vf[0], o0);
    o0 = mfma32(pa1.v8, vf[1], o0);
    o1 = mfma32(pa0.v8, vf[2], o1);
    o1 = mfma32(pa1.v8, vf[3], o1);
  };

  bf16x8 kfA[4], vfA[4], kfB[4], vfB[4];
#pragma unroll
  for (int ck = 0; ck < 4; ck++)
    kfA[ck] = *reinterpret_cast<const bf16x8*>(Krow + ck * 16);
  vfA[0] = *reinterpret_cast<const bf16x8*>(V0);
  vfA[1] = *reinterpret_cast<const bf16x8*>(V0 + 16);
  vfA[2] = *reinterpret_cast<const bf16x8*>(V1);
  vfA[3] = *reinterpret_cast<const bf16x8*>(V1 + 16);

  for (int i = 0; i < 32; ++i) {
    const int t1 = 2 * i + 1;
#pragma unroll
    for (int ck = 0; ck < 4; ck++)
      kfB[ck] = *reinterpret_cast<const bf16x8*>(Krow + t1 * 2048 + ck * 16);
    vfB[0] = *reinterpret_cast<const bf16x8*>(V0 + t1 * 32);
    vfB[1] = *reinterpret_cast<const bf16x8*>(V0 + t1 * 32 + 16);
    vfB[2] = *reinterpret_cast<const bf16x8*>(V1 + t1 * 32);
    vfB[3] = *reinterpret_cast<const bf16x8*>(V1 + t1 * 32 + 16);
    mwn = Mrow[i + 1 < 32 ? i + 1 : 31];

    comp(kfA, vfA, 0);

    if (i < 31) {
      const int t2 = 2 * i + 2;
#pragma unroll
      for (int ck = 0; ck < 4; ck++)
        kfA[ck] = *reinterpret_cast<const bf16x8*>(Krow + t2 * 2048 + ck * 16);
      vfA[0] = *reinterpret_cast<const bf16x8*>(V0 + t2 * 32);
      vfA[1] = *reinterpret_cast<const bf16x8*>(V0 + t2 * 32 + 16);
      vfA[2] = *reinterpret_cast<const bf16x8*>(V1 + t2 * 32);
      vfA[3] = *reinterpret_cast<const bf16x8*>(V1 + t2 * 32 + 16);
    }

    comp(kfB, vfB, 32);

    mw = mwn;
    skipm = __all(mw == ~0ull);
  }

  float linv = 1.0f / lrun;
  size_t obase = ((size_t)b * 2048 + q0) * 1024 + (size_t)h * 64 + l31;
#pragma unroll
  for (int r = 0; r < 16; r++) {
    int cr = (r & 3) + 8 * (r >> 2);
    int rho = cr + lh4;
    float li = __shfl(linv, rho);
    ctx[obase + (size_t)rho * 1024] = __float2bfloat16(o0[r] * li);
    ctx[obase + (size_t)rho * 1024 + 32] = __float2bfloat16(o1[r] * li);
  }
}

extern "C" void kernel_launch(void* const* d_in, const int* in_sizes, int n_in,
                              void* d_out, int out_size, void* d_ws,
                              size_t ws_size, hipStream_t stream) {
  const float* x = (const float*)d_in[0];
  const int* mask = (const int*)d_in[1];
  const float* Wq = (const float*)d_in[2];
  const float* bq = (const float*)d_in[3];
  const float* Wk = (const float*)d_in[4];
  const float* bk = (const float*)d_in[5];
  const float* Wv = (const float*)d_in[6];
  const float* bv = (const float*)d_in[7];
  const float* Wo = (const float*)d_in[8];
  const float* bo = (const float*)d_in[9];
  float* out = (float*)d_out;  // reference output dtype is float32
  char* ws = (char*)d_ws;

  // ws layout (bytes)
  __hip_bfloat16* xb   = (__hip_bfloat16*)(ws);              // 8 MiB
  __hip_bfloat16* wqkv = (__hip_bfloat16*)(ws + 8388608);    // 6 MiB
  __hip_bfloat16* wo   = (__hip_bfloat16*)(ws + 14680064);   // 2 MiB
  __hip_bfloat16* qws  = (__hip_bfloat16*)(ws + 16777216);   // 8 MiB
  __hip_bfloat16* kws  = (__hip_bfloat16*)(ws + 25165824);   // 8 MiB
  __hip_bfloat16* vtmp = (__hip_bfloat16*)(ws + 33554432);   // 8 MiB
  __hip_bfloat16* vt   = (__hip_bfloat16*)(ws + 41943040);   // 8 MiB
  __hip_bfloat16* ctx  = (__hip_bfloat16*)(ws + 50331648);   // 8 MiB
  unsigned long long* mbits = (unsigned long long*)(ws + 58720256);  // 1 MiB

  castf2b<<<4096, 256, 0, stream>>>(x, xb, 4194304);
  castf2b<<<1024, 256, 0, stream>>>(Wq, wqkv, 1048576);
  castf2b<<<1024, 256, 0, stream>>>(Wk, wqkv + 1048576, 1048576);
  castf2b<<<1024, 256, 0, stream>>>(Wv, wqkv + 2097152, 1048576);
  castf2b<<<1024, 256, 0, stream>>>(Wo, wo, 1048576);
  mask_pack<<<32768, 256, 0, stream>>>(mask, mbits);

  gemm_bt<0><<<768, 256, 0, stream>>>(xb, wqkv, bq, bk, bv, qws, kws, vtmp,
                                      nullptr, 4096, 3072, 1024);
  vtrans<<<1024, 256, 0, stream>>>(vtmp, vt);
  attn2<<<512, 256, 0, stream>>>(qws, kws, vt, mbits, ctx);
  gemm_bt<1><<<256, 256, 0, stream>>>(ctx, wo, bo, nullptr, nullptr, nullptr,
                                      nullptr, nullptr, out, 4096, 1024, 1024);
}

// Round 12
// 346.069 us; speedup vs baseline: 1.1120x; 1.0178x over previous
//
#include <hip/hip_runtime.h>
#include <hip/hip_bf16.h>

typedef __attribute__((ext_vector_type(8))) short bf16x8;
typedef __attribute__((ext_vector_type(4))) float f32x4;
typedef __attribute__((ext_vector_type(16))) float f32x16;
typedef unsigned int uint;

typedef __attribute__((address_space(1))) void as1_void;
typedef __attribute__((address_space(3))) void as3_void;

__device__ __forceinline__ void gload16(const void* g, void* l) {
  __builtin_amdgcn_global_load_lds((as1_void*)(void*)g, (as3_void*)l, 16, 0, 0);
}

__device__ __forceinline__ f32x4 mfma16(bf16x8 a, bf16x8 b, f32x4 c) {
  return __builtin_amdgcn_mfma_f32_16x16x32_bf16(a, b, c, 0, 0, 0);
}

__device__ __forceinline__ f32x16 mfma32(bf16x8 a, bf16x8 b, f32x16 c) {
  return __builtin_amdgcn_mfma_f32_32x32x16_bf16(a, b, c, 0, 0, 0);
}

// ---------------- cast fp32 -> bf16, 4 elems/thread ----------------
__global__ __launch_bounds__(256) void castf2b(const float* __restrict__ s,
                                               __hip_bfloat16* __restrict__ d, int n) {
  int i = (blockIdx.x * 256 + threadIdx.x) * 4;
  if (i >= n) return;
  float4 f = *reinterpret_cast<const float4*>(s + i);
  union { __hip_bfloat16 h[4]; uint2 u; } cv;
  cv.h[0] = __float2bfloat16(f.x);
  cv.h[1] = __float2bfloat16(f.y);
  cv.h[2] = __float2bfloat16(f.z);
  cv.h[3] = __float2bfloat16(f.w);
  *reinterpret_cast<uint2*>(d + i) = cv.u;
}

// ---------------- cast all 4 weight matrices in one launch ----------------
__global__ __launch_bounds__(256) void castw(
    const float* __restrict__ Wq, const float* __restrict__ Wk,
    const float* __restrict__ Wv, const float* __restrict__ Wo,
    __hip_bfloat16* __restrict__ wqkv, __hip_bfloat16* __restrict__ wo) {
  int seg = blockIdx.x >> 10;
  int i = ((blockIdx.x & 1023) * 256 + threadIdx.x) * 4;
  const float* s = seg == 0 ? Wq : seg == 1 ? Wk : seg == 2 ? Wv : Wo;
  __hip_bfloat16* d = seg < 3 ? wqkv + seg * 1048576 : wo;
  float4 f = *reinterpret_cast<const float4*>(s + i);
  union { __hip_bfloat16 h[4]; uint2 u; } cv;
  cv.h[0] = __float2bfloat16(f.x);
  cv.h[1] = __float2bfloat16(f.y);
  cv.h[2] = __float2bfloat16(f.z);
  cv.h[3] = __float2bfloat16(f.w);
  *reinterpret_cast<uint2*>(d + i) = cv.u;
}

// ---------------- pack int32 mask -> bitmask (1 bit per element) ----------------
__global__ __launch_bounds__(256) void mask_pack(const int* __restrict__ m,
                                                 unsigned long long* __restrict__ bits) {
  int g = blockIdx.x * 256 + threadIdx.x;
  unsigned long long bal = __ballot(m[g] != 0);
  if ((threadIdx.x & 63) == 0) bits[g >> 6] = bal;
}

// ---------------- V transpose: [bh][2048][64] -> [bh][64][2048] ----------------
__global__ __launch_bounds__(256) void vtrans(const __hip_bfloat16* __restrict__ v,
                                              __hip_bfloat16* __restrict__ vt) {
  int bh = blockIdx.x >> 5;
  int s0 = (blockIdx.x & 31) * 64;
  __shared__ __align__(16) __hip_bfloat16 tile[64][72];
  const __hip_bfloat16* src = v + ((size_t)bh * 2048 + s0) * 64;
  int t = threadIdx.x;
#pragma unroll
  for (int i = 0; i < 2; i++) {
    int c = t + i * 256;
    int r = c >> 3, c8 = (c & 7) * 8;
    *reinterpret_cast<uint4*>(&tile[r][c8]) =
        *reinterpret_cast<const uint4*>(src + (size_t)r * 64 + c8);
  }
  __syncthreads();
  __hip_bfloat16* dst = vt + (size_t)bh * 64 * 2048 + s0;
#pragma unroll
  for (int i = 0; i < 2; i++) {
    int c = t + i * 256;
    int d = c >> 3, s8 = (c & 7) * 8;
    __hip_bfloat16 tmp[8] __attribute__((aligned(16)));
#pragma unroll
    for (int j = 0; j < 8; j++) tmp[j] = tile[s8 + j][d];
    *reinterpret_cast<uint4*>(dst + (size_t)d * 2048 + s8) =
        *reinterpret_cast<const uint4*>(tmp);
  }
}

// ---------------- GEMM C = A * B^T (+bias), 128x128x64 tile, 4 waves ----------------
template <int MODE>
__global__ __launch_bounds__(256) void gemm_bt(
    const __hip_bfloat16* __restrict__ A, const __hip_bfloat16* __restrict__ Bw,
    const float* __restrict__ bias0, const float* __restrict__ bias1,
    const float* __restrict__ bias2, __hip_bfloat16* __restrict__ out0,
    __hip_bfloat16* __restrict__ out1, __hip_bfloat16* __restrict__ out2,
    float* __restrict__ foutp, int M, int N, int K) {
  __shared__ __align__(16) __hip_bfloat16 Alds[128 * 64];
  __shared__ __align__(16) __hip_bfloat16 Blds[128 * 64];
  const int t = threadIdx.x;
  const int lane = t & 63;
  const int w = t >> 6;
  const int wr = w >> 1, wc = w & 1;
  const int l15 = lane & 15, lhi = lane >> 4;
  const int Nt = N >> 7;
  const int bm = (int)blockIdx.x / Nt, bn = (int)blockIdx.x % Nt;
  const int m0 = bm * 128, n0 = bn * 128;

  const f32x4 fzero = {0.f, 0.f, 0.f, 0.f};
  f32x4 acc[4][4];
#pragma unroll
  for (int mi = 0; mi < 4; mi++)
#pragma unroll
    for (int ni = 0; ni < 4; ni++) acc[mi][ni] = fzero;

  for (int k0 = 0; k0 < K; k0 += 64) {
#pragma unroll
    for (int i = 0; i < 4; i++) {
      int c = t + i * 256;           // 16B chunk id, 1024 per tile
      int r = c >> 3, c8 = (c & 7) * 8;
      gload16(A + (size_t)(m0 + r) * K + k0 + c8, (char*)Alds + c * 16);
      gload16(Bw + (size_t)(n0 + r) * K + k0 + c8, (char*)Blds + c * 16);
    }
    __syncthreads();
#pragma unroll
    for (int kk = 0; kk < 2; kk++) {
      bf16x8 af[4], bfr[4];
#pragma unroll
      for (int mi = 0; mi < 4; mi++)
        af[mi] = *reinterpret_cast<const bf16x8*>(
            &Alds[(wr * 64 + mi * 16 + l15) * 64 + kk * 32 + lhi * 8]);
#pragma unroll
      for (int ni = 0; ni < 4; ni++)
        bfr[ni] = *reinterpret_cast<const bf16x8*>(
            &Blds[(wc * 64 + ni * 16 + l15) * 64 + kk * 32 + lhi * 8]);
#pragma unroll
      for (int mi = 0; mi < 4; mi++)
#pragma unroll
        for (int ni = 0; ni < 4; ni++)
          acc[mi][ni] = mfma16(af[mi], bfr[ni], acc[mi][ni]);
    }
    __syncthreads();
  }

#pragma unroll
  for (int mi = 0; mi < 4; mi++) {
#pragma unroll
    for (int ni = 0; ni < 4; ni++) {
#pragma unroll
      for (int r = 0; r < 4; r++) {
        int gr = m0 + wr * 64 + mi * 16 + lhi * 4 + r;
        int gc = n0 + wc * 64 + ni * 16 + l15;
        float v = acc[mi][ni][r];
        if (MODE == 0) {
          int seg = gc >> 10, e = gc & 1023, h = e >> 6, d = e & 63;
          int b = gr >> 11, s = gr & 2047;
          size_t idx = (((size_t)(b * 16 + h)) * 2048 + s) * 64 + d;
          if (seg == 0)
            out0[idx] = __float2bfloat16((v + bias0[e]) * 0.125f);
          else if (seg == 1)
            out1[idx] = __float2bfloat16(v + bias1[e]);
          else
            out2[idx] = __float2bfloat16(v + bias2[e]);
        } else {
          foutp[(size_t)gr * N + gc] = v + bias0[gc];
        }
      }
    }
  }
}

// ---------------- Flash attention v3: swapped-QK 32x32, KV-split ------------
// Q,K: [bh][2048][64] (Q pre-scaled 1/8); VT: [bh][64][2048]; mb: [b][2048][32]
// u64 bitmask; ctx: [b][s][h*64+d] bf16.
// 1024 blocks x 4 waves. Waves {0,1}: kv[0,1024); waves {2,3}: kv[1024,2048).
// Wave w covers q-sub (w&1): 32 q rows. Partial (m,l,o) merged via LDS.
// o-exchange LDS layout [reg][lane] (conflict-free; [lane][reg] = 64-way).
// Cross-half scalar reduces use __shfl_xor(.,32) (permlane self-swap UNSAFE,
// round-9). cvt_pk+permlane on distinct values (T12) kept. Defer-max (T13).
__global__ __launch_bounds__(256) void attn2(
    const __hip_bfloat16* __restrict__ Q, const __hip_bfloat16* __restrict__ Kk,
    const __hip_bfloat16* __restrict__ VT,
    const unsigned long long* __restrict__ mb, __hip_bfloat16* __restrict__ ctx) {
  int bx = blockIdx.x;
  int bid = (bx & 7) * 128 + (bx >> 3);  // XCD swizzle, bijective (1024 = 8*128)
  int bh = bid >> 5, qc = bid & 31;
  int b = bh >> 4, h = bh & 15;
  int lane = threadIdx.x & 63, w = threadIdx.x >> 6;
  int l31 = lane & 31, lh = lane >> 5, lh4 = lh * 4;
  int wsb = w & 1;        // q-sub within block
  int kvh = w >> 1;       // kv half
  int q0 = qc * 64 + wsb * 32;
  int kvbase = kvh * 1024;

  __shared__ float olds[2][32][64];   // [q-sub][reg 0..31][lane] hi-wave o
  __shared__ float mlds[2][2][32];    // [q-sub][kv-half][q]
  __shared__ float llds[2][2][32];

  const __hip_bfloat16* Qrow = Q + ((size_t)bh * 2048 + q0 + l31) * 64 + lh * 8;
  const __hip_bfloat16* Krow =
      Kk + ((size_t)bh * 2048 + kvbase + l31) * 64 + lh * 8;
  const __hip_bfloat16* V0 =
      VT + ((size_t)bh * 64 + l31) * 2048 + kvbase + lh * 8;
  const __hip_bfloat16* V1 = V0 + 32 * 2048;
  const unsigned long long* Mrow =
      mb + ((size_t)b * 2048 + q0 + l31) * 32 + kvh * 16;

  bf16x8 qf[4];
#pragma unroll
  for (int ck = 0; ck < 4; ck++)
    qf[ck] = *reinterpret_cast<const bf16x8*>(Qrow + ck * 16);

  f32x16 o0 = {}, o1 = {};
  float mrun = -3.0e38f, lrun = 0.f;

  unsigned long long mw = Mrow[0], mwn = 0;
  bool skipm = __all(mw == ~0ull);

  // one 32-kv tile: QK^T -> mask -> online softmax (in-register) -> PV
  auto comp = [&](const bf16x8* kf, const bf16x8* vf, int sh) {
    f32x16 s = {};
#pragma unroll
    for (int ck = 0; ck < 4; ck++) s = mfma32(kf[ck], qf[ck], s);
    if (!skipm) {
      uint mh = (uint)(mw >> sh) >> lh4;
#pragma unroll
      for (int r = 0; r < 16; r++) {
        int cr = (r & 3) + 8 * (r >> 2);
        if (!((mh >> cr) & 1u)) s[r] = -1e9f;
      }
    }
    float pmax = s[0];
#pragma unroll
    for (int r = 1; r < 16; r++) pmax = fmaxf(pmax, s[r]);
    pmax = fmaxf(pmax, __shfl_xor(pmax, 32));  // cross-half max
    if (!__all(pmax <= mrun + 8.0f)) {  // defer-max (T13), wave-uniform
      float nm = fmaxf(mrun, pmax);
      float scl = __expf(mrun - nm);
      mrun = nm;
      lrun *= scl;
#pragma unroll
      for (int r = 0; r < 16; r++) {
        int cr = (r & 3) + 8 * (r >> 2);
        float sr = __shfl(scl, cr + lh4);
        o0[r] *= sr;
        o1[r] *= sr;
      }
    }
    float p[16];
    float ts = 0.f;
#pragma unroll
    for (int r = 0; r < 16; r++) {
      p[r] = __expf(s[r] - mrun);
      ts += p[r];
    }
    ts += __shfl_xor(ts, 32);  // cross-half sum
    lrun += ts;
    uint x0, x1, x2, x3, y0, y1, y2, y3;
    asm("v_cvt_pk_bf16_f32 %0, %1, %2" : "=v"(x0) : "v"(p[0]), "v"(p[1]));
    asm("v_cvt_pk_bf16_f32 %0, %1, %2" : "=v"(y0) : "v"(p[4]), "v"(p[5]));
    asm("v_cvt_pk_bf16_f32 %0, %1, %2" : "=v"(x1) : "v"(p[2]), "v"(p[3]));
    asm("v_cvt_pk_bf16_f32 %0, %1, %2" : "=v"(y1) : "v"(p[6]), "v"(p[7]));
    asm("v_cvt_pk_bf16_f32 %0, %1, %2" : "=v"(x2) : "v"(p[8]), "v"(p[9]));
    asm("v_cvt_pk_bf16_f32 %0, %1, %2" : "=v"(y2) : "v"(p[12]), "v"(p[13]));
    asm("v_cvt_pk_bf16_f32 %0, %1, %2" : "=v"(x3) : "v"(p[10]), "v"(p[11]));
    asm("v_cvt_pk_bf16_f32 %0, %1, %2" : "=v"(y3) : "v"(p[14]), "v"(p[15]));
    asm volatile("v_permlane32_swap_b32 %0, %1" : "+v"(x0), "+v"(y0));
    asm volatile("v_permlane32_swap_b32 %0, %1" : "+v"(x1), "+v"(y1));
    asm volatile("v_permlane32_swap_b32 %0, %1" : "+v"(x2), "+v"(y2));
    asm volatile("v_permlane32_swap_b32 %0, %1" : "+v"(x3), "+v"(y3));
    union { uint u[4]; bf16x8 v8; } pa0, pa1;
    pa0.u[0] = x0; pa0.u[1] = x1; pa0.u[2] = y0; pa0.u[3] = y1;
    pa1.u[0] = x2; pa1.u[1] = x3; pa1.u[2] = y2; pa1.u[3] = y3;
    o0 = mfma32(pa0.v8, vf[0], o0);
    o0 = mfma32(pa1.v8, vf[1], o0);
    o1 = mfma32(pa0.v8, vf[2], o1);
    o1 = mfma32(pa1.v8, vf[3], o1);
  };

  bf16x8 kfA[4], vfA[4], kfB[4], vfB[4];
#pragma unroll
  for (int ck = 0; ck < 4; ck++)
    kfA[ck] = *reinterpret_cast<const bf16x8*>(Krow + ck * 16);
  vfA[0] = *reinterpret_cast<const bf16x8*>(V0);
  vfA[1] = *reinterpret_cast<const bf16x8*>(V0 + 16);
  vfA[2] = *reinterpret_cast<const bf16x8*>(V1);
  vfA[3] = *reinterpret_cast<const bf16x8*>(V1 + 16);

  for (int i = 0; i < 16; ++i) {
    const int t1 = 2 * i + 1;
#pragma unroll
    for (int ck = 0; ck < 4; ck++)
      kfB[ck] = *reinterpret_cast<const bf16x8*>(Krow + t1 * 2048 + ck * 16);
    vfB[0] = *reinterpret_cast<const bf16x8*>(V0 + t1 * 32);
    vfB[1] = *reinterpret_cast<const bf16x8*>(V0 + t1 * 32 + 16);
    vfB[2] = *reinterpret_cast<const bf16x8*>(V1 + t1 * 32);
    vfB[3] = *reinterpret_cast<const bf16x8*>(V1 + t1 * 32 + 16);
    mwn = Mrow[i + 1 < 16 ? i + 1 : 15];

    comp(kfA, vfA, 0);

    if (i < 15) {
      const int t2 = 2 * i + 2;
#pragma unroll
      for (int ck = 0; ck < 4; ck++)
        kfA[ck] = *reinterpret_cast<const bf16x8*>(Krow + t2 * 2048 + ck * 16);
      vfA[0] = *reinterpret_cast<const bf16x8*>(V0 + t2 * 32);
      vfA[1] = *reinterpret_cast<const bf16x8*>(V0 + t2 * 32 + 16);
      vfA[2] = *reinterpret_cast<const bf16x8*>(V1 + t2 * 32);
      vfA[3] = *reinterpret_cast<const bf16x8*>(V1 + t2 * 32 + 16);
    }

    comp(kfB, vfB, 32);

    mw = mwn;
    skipm = __all(mw == ~0ull);
  }

  // ---- merge kv-halves (waves w and w+2 share q-sub wsb) ----
  if (lh == 0) {
    mlds[wsb][kvh][l31] = mrun;
    llds[wsb][kvh][l31] = lrun;
  }
  __syncthreads();
  float mA = mlds[wsb][0][l31], mB = mlds[wsb][1][l31];
  float lA = llds[wsb][0][l31], lB = llds[wsb][1][l31];
  float mN = fmaxf(mA, mB);
  float aA = __expf(mA - mN), aB = __expf(mB - mN);
  if (kvh) {  // high wave: scale own o, deposit to LDS
#pragma unroll
    for (int r = 0; r < 16; r++) {
      int cr = (r & 3) + 8 * (r >> 2);
      float ar = __shfl(aB, cr + lh4);
      olds[wsb][r][lane] = o0[r] * ar;
      olds[wsb][16 + r][lane] = o1[r] * ar;
    }
  }
  __syncthreads();
  if (!kvh) {  // low wave: merge + epilogue
    float linv = 1.0f / (lA * aA + lB * aB);
    size_t obase = ((size_t)b * 2048 + q0) * 1024 + (size_t)h * 64 + l31;
#pragma unroll
    for (int r = 0; r < 16; r++) {
      int cr = (r & 3) + 8 * (r >> 2);
      int rho = cr + lh4;
      float ar = __shfl(aA, rho);
      float li = __shfl(linv, rho);
      float v0 = o0[r] * ar + olds[wsb][r][lane];
      float v1 = o1[r] * ar + olds[wsb][16 + r][lane];
      ctx[obase + (size_t)rho * 1024] = __float2bfloat16(v0 * li);
      ctx[obase + (size_t)rho * 1024 + 32] = __float2bfloat16(v1 * li);
    }
  }
}

extern "C" void kernel_launch(void* const* d_in, const int* in_sizes, int n_in,
                              void* d_out, int out_size, void* d_ws,
                              size_t ws_size, hipStream_t stream) {
  const float* x = (const float*)d_in[0];
  const int* mask = (const int*)d_in[1];
  const float* Wq = (const float*)d_in[2];
  const float* bq = (const float*)d_in[3];
  const float* Wk = (const float*)d_in[4];
  const float* bk = (const float*)d_in[5];
  const float* Wv = (const float*)d_in[6];
  const float* bv = (const float*)d_in[7];
  const float* Wo = (const float*)d_in[8];
  const float* bo = (const float*)d_in[9];
  float* out = (float*)d_out;  // reference output dtype is float32
  char* ws = (char*)d_ws;

  // ws layout (bytes)
  __hip_bfloat16* xb   = (__hip_bfloat16*)(ws);              // 8 MiB
  __hip_bfloat16* wqkv = (__hip_bfloat16*)(ws + 8388608);    // 6 MiB
  __hip_bfloat16* wo   = (__hip_bfloat16*)(ws + 14680064);   // 2 MiB
  __hip_bfloat16* qws  = (__hip_bfloat16*)(ws + 16777216);   // 8 MiB
  __hip_bfloat16* kws  = (__hip_bfloat16*)(ws + 25165824);   // 8 MiB
  __hip_bfloat16* vtmp = (__hip_bfloat16*)(ws + 33554432);   // 8 MiB
  __hip_bfloat16* vt   = (__hip_bfloat16*)(ws + 41943040);   // 8 MiB
  __hip_bfloat16* ctx  = (__hip_bfloat16*)(ws + 50331648);   // 8 MiB
  unsigned long long* mbits = (unsigned long long*)(ws + 58720256);  // 1 MiB

  castf2b<<<4096, 256, 0, stream>>>(x, xb, 4194304);
  castw<<<4096, 256, 0, stream>>>(Wq, Wk, Wv, Wo, wqkv, wo);
  mask_pack<<<32768, 256, 0, stream>>>(mask, mbits);

  gemm_bt<0><<<768, 256, 0, stream>>>(xb, wqkv, bq, bk, bv, qws, kws, vtmp,
                                      nullptr, 4096, 3072, 1024);
  vtrans<<<1024, 256, 0, stream>>>(vtmp, vt);
  attn2<<<1024, 256, 0, stream>>>(qws, kws, vt, mbits, ctx);
  gemm_bt<1><<<256, 256, 0, stream>>>(ctx, wo, bo, nullptr, nullptr, nullptr,
                                      nullptr, nullptr, out, 4096, 1024, 1024);
}

// Round 13
// 300.293 us; speedup vs baseline: 1.2816x; 1.1524x over previous
//
#include <hip/hip_runtime.h>
#include <hip/hip_bf16.h>

typedef __attribute__((ext_vector_type(8))) short bf16x8;
typedef __attribute__((ext_vector_type(4))) float f32x4;
typedef __attribute__((ext_vector_type(16))) float f32x16;
typedef unsigned int uint;

typedef __attribute__((address_space(1))) void as1_void;
typedef __attribute__((address_space(3))) void as3_void;

__device__ __forceinline__ void gload16(const void* g, void* l) {
  __builtin_amdgcn_global_load_lds((as1_void*)(void*)g, (as3_void*)l, 16, 0, 0);
}

__device__ __forceinline__ f32x4 mfma16(bf16x8 a, bf16x8 b, f32x4 c) {
  return __builtin_amdgcn_mfma_f32_16x16x32_bf16(a, b, c, 0, 0, 0);
}

__device__ __forceinline__ f32x16 mfma32(bf16x8 a, bf16x8 b, f32x16 c) {
  return __builtin_amdgcn_mfma_f32_32x32x16_bf16(a, b, c, 0, 0, 0);
}

// ---------------- cast fp32 -> bf16, 4 elems/thread ----------------
__global__ __launch_bounds__(256) void castf2b(const float* __restrict__ s,
                                               __hip_bfloat16* __restrict__ d, int n) {
  int i = (blockIdx.x * 256 + threadIdx.x) * 4;
  if (i >= n) return;
  float4 f = *reinterpret_cast<const float4*>(s + i);
  union { __hip_bfloat16 h[4]; uint2 u; } cv;
  cv.h[0] = __float2bfloat16(f.x);
  cv.h[1] = __float2bfloat16(f.y);
  cv.h[2] = __float2bfloat16(f.z);
  cv.h[3] = __float2bfloat16(f.w);
  *reinterpret_cast<uint2*>(d + i) = cv.u;
}

// ---------------- cast all 4 weight matrices in one launch ----------------
__global__ __launch_bounds__(256) void castw(
    const float* __restrict__ Wq, const float* __restrict__ Wk,
    const float* __restrict__ Wv, const float* __restrict__ Wo,
    __hip_bfloat16* __restrict__ wqkv, __hip_bfloat16* __restrict__ wo) {
  int seg = blockIdx.x >> 10;
  int i = ((blockIdx.x & 1023) * 256 + threadIdx.x) * 4;
  const float* s = seg == 0 ? Wq : seg == 1 ? Wk : seg == 2 ? Wv : Wo;
  __hip_bfloat16* d = seg < 3 ? wqkv + seg * 1048576 : wo;
  float4 f = *reinterpret_cast<const float4*>(s + i);
  union { __hip_bfloat16 h[4]; uint2 u; } cv;
  cv.h[0] = __float2bfloat16(f.x);
  cv.h[1] = __float2bfloat16(f.y);
  cv.h[2] = __float2bfloat16(f.z);
  cv.h[3] = __float2bfloat16(f.w);
  *reinterpret_cast<uint2*>(d + i) = cv.u;
}

// ---------------- pack int32 mask -> bitmask (1 bit per element) ----------------
__global__ __launch_bounds__(256) void mask_pack(const int* __restrict__ m,
                                                 unsigned long long* __restrict__ bits) {
  int g = blockIdx.x * 256 + threadIdx.x;
  unsigned long long bal = __ballot(m[g] != 0);
  if ((threadIdx.x & 63) == 0) bits[g >> 6] = bal;
}

// ---------------- V transpose: [bh][2048][64] -> [bh][64][2048] ----------------
__global__ __launch_bounds__(256) void vtrans(const __hip_bfloat16* __restrict__ v,
                                              __hip_bfloat16* __restrict__ vt) {
  int bh = blockIdx.x >> 5;
  int s0 = (blockIdx.x & 31) * 64;
  __shared__ __align__(16) __hip_bfloat16 tile[64][72];
  const __hip_bfloat16* src = v + ((size_t)bh * 2048 + s0) * 64;
  int t = threadIdx.x;
#pragma unroll
  for (int i = 0; i < 2; i++) {
    int c = t + i * 256;
    int r = c >> 3, c8 = (c & 7) * 8;
    *reinterpret_cast<uint4*>(&tile[r][c8]) =
        *reinterpret_cast<const uint4*>(src + (size_t)r * 64 + c8);
  }
  __syncthreads();
  __hip_bfloat16* dst = vt + (size_t)bh * 64 * 2048 + s0;
#pragma unroll
  for (int i = 0; i < 2; i++) {
    int c = t + i * 256;
    int d = c >> 3, s8 = (c & 7) * 8;
    __hip_bfloat16 tmp[8] __attribute__((aligned(16)));
#pragma unroll
    for (int j = 0; j < 8; j++) tmp[j] = tile[s8 + j][d];
    *reinterpret_cast<uint4*>(dst + (size_t)d * 2048 + s8) =
        *reinterpret_cast<const uint4*>(tmp);
  }
}

// ---------------- GEMM C = A * B^T (+bias), 128x128x64 tile, 4 waves ----------------
template <int MODE>
__global__ __launch_bounds__(256) void gemm_bt(
    const __hip_bfloat16* __restrict__ A, const __hip_bfloat16* __restrict__ Bw,
    const float* __restrict__ bias0, const float* __restrict__ bias1,
    const float* __restrict__ bias2, __hip_bfloat16* __restrict__ out0,
    __hip_bfloat16* __restrict__ out1, __hip_bfloat16* __restrict__ out2,
    float* __restrict__ foutp, int M, int N, int K) {
  __shared__ __align__(16) __hip_bfloat16 Alds[128 * 64];
  __shared__ __align__(16) __hip_bfloat16 Blds[128 * 64];
  const int t = threadIdx.x;
  const int lane = t & 63;
  const int w = t >> 6;
  const int wr = w >> 1, wc = w & 1;
  const int l15 = lane & 15, lhi = lane >> 4;
  const int Nt = N >> 7;
  const int bm = (int)blockIdx.x / Nt, bn = (int)blockIdx.x % Nt;
  const int m0 = bm * 128, n0 = bn * 128;

  const f32x4 fzero = {0.f, 0.f, 0.f, 0.f};
  f32x4 acc[4][4];
#pragma unroll
  for (int mi = 0; mi < 4; mi++)
#pragma unroll
    for (int ni = 0; ni < 4; ni++) acc[mi][ni] = fzero;

  for (int k0 = 0; k0 < K; k0 += 64) {
#pragma unroll
    for (int i = 0; i < 4; i++) {
      int c = t + i * 256;           // 16B chunk id, 1024 per tile
      int r = c >> 3, c8 = (c & 7) * 8;
      gload16(A + (size_t)(m0 + r) * K + k0 + c8, (char*)Alds + c * 16);
      gload16(Bw + (size_t)(n0 + r) * K + k0 + c8, (char*)Blds + c * 16);
    }
    __syncthreads();
#pragma unroll
    for (int kk = 0; kk < 2; kk++) {
      bf16x8 af[4], bfr[4];
#pragma unroll
      for (int mi = 0; mi < 4; mi++)
        af[mi] = *reinterpret_cast<const bf16x8*>(
            &Alds[(wr * 64 + mi * 16 + l15) * 64 + kk * 32 + lhi * 8]);
#pragma unroll
      for (int ni = 0; ni < 4; ni++)
        bfr[ni] = *reinterpret_cast<const bf16x8*>(
            &Blds[(wc * 64 + ni * 16 + l15) * 64 + kk * 32 + lhi * 8]);
#pragma unroll
      for (int mi = 0; mi < 4; mi++)
#pragma unroll
        for (int ni = 0; ni < 4; ni++)
          acc[mi][ni] = mfma16(af[mi], bfr[ni], acc[mi][ni]);
    }
    __syncthreads();
  }

#pragma unroll
  for (int mi = 0; mi < 4; mi++) {
#pragma unroll
    for (int ni = 0; ni < 4; ni++) {
#pragma unroll
      for (int r = 0; r < 4; r++) {
        int gr = m0 + wr * 64 + mi * 16 + lhi * 4 + r;
        int gc = n0 + wc * 64 + ni * 16 + l15;
        float v = acc[mi][ni][r];
        if (MODE == 0) {
          int seg = gc >> 10, e = gc & 1023, h = e >> 6, d = e & 63;
          int b = gr >> 11, s = gr & 2047;
          size_t idx = (((size_t)(b * 16 + h)) * 2048 + s) * 64 + d;
          if (seg == 0)
            out0[idx] = __float2bfloat16((v + bias0[e]) * 0.125f);
          else if (seg == 1)
            out1[idx] = __float2bfloat16(v + bias1[e]);
          else
            out2[idx] = __float2bfloat16(v + bias2[e]);
        } else {
          foutp[(size_t)gr * N + gc] = v + bias0[gc];
        }
      }
    }
  }
}

// ---------------- Flash attention v4: LDS-staged KV, transposed-chunk layout -
// Q,K: [bh][2048][64] (Q pre-scaled 1/8); VT: [bh][64][2048]; mb u64 bitmask;
// ctx: [b][s][h*64+d] bf16.
// 1024 blocks x 4 waves, __launch_bounds__(256,4) => <=128 regs, 4 waves/SIMD
// (round-12 lesson: 124 VGPR + AGPRs -> 256-granule -> 2 waves/SIMD cap).
// Waves: wsb=w&1 (q-sub, 32 rows), kvh=w>>1 (kv half). KVBLK=32, dbuf LDS,
// 1 barrier/iter (round-8-verified). LDS tiles use TRANSPOSED CHUNK layout:
// chunk(s,r) at linear s*R+r => every ds_read_b128 is 32 lanes x contiguous
// 16B = conflict-free, and gload_lds dests stay linear (rule #21 trivially).
// In-reg swapped-QK softmax (round-10-verified); merge (round-12-verified).
__global__ __launch_bounds__(256, 4) void attn3(
    const __hip_bfloat16* __restrict__ Q, const __hip_bfloat16* __restrict__ Kk,
    const __hip_bfloat16* __restrict__ VT,
    const unsigned long long* __restrict__ mb, __hip_bfloat16* __restrict__ ctx) {
  int bx = blockIdx.x;
  int bid = (bx & 7) * 128 + (bx >> 3);  // XCD swizzle, bijective (1024 = 8*128)
  int bh = bid >> 5, qc = bid & 31;
  int b = bh >> 4, h = bh & 15;
  int lane = threadIdx.x & 63, w = threadIdx.x >> 6;
  int l31 = lane & 31, lh = lane >> 5, lh4 = lh * 4;
  int wsb = w & 1;        // q-sub within block
  int kvh = w >> 1;       // kv half
  int q0 = qc * 64 + wsb * 32;

  // [buf][section: K half0, K half1, V half0, V half1][4KB]
  __shared__ __align__(16) char tiles[2][4][4096];
  __shared__ float mlds[2][2][32];
  __shared__ float llds[2][2][32];
  float* olds = (float*)&tiles[0][0][0];  // merge scratch overlays tiles (16KB)

  const int t = threadIdx.x;
  const __hip_bfloat16* Kg = Kk + (size_t)bh * 2048 * 64;
  const __hip_bfloat16* Vg = VT + (size_t)bh * 64 * 2048;
  const unsigned long long* Mrow =
      mb + ((size_t)b * 2048 + q0 + l31) * 32 + kvh * 16;

  bf16x8 qf[4];
  {
    const __hip_bfloat16* Qrow =
        Q + ((size_t)bh * 2048 + q0 + l31) * 64 + lh * 8;
#pragma unroll
    for (int ck = 0; ck < 4; ck++)
      qf[ck] = *reinterpret_cast<const bf16x8*>(Qrow + ck * 16);
  }

  // stage tile kvt (32 kv per half, both halves) into buffer buf
  auto stage = [&](int buf, int kvt) {
    {  // K half0/half1: chunk = s*32 + r  (s = d-slot 0..7, r = kv 0..31)
      int r = t & 31, s = t >> 5;
      gload16(Kg + (size_t)(kvt * 32 + r) * 64 + s * 8,
              &tiles[buf][0][t * 16]);
      gload16(Kg + (size_t)(1024 + kvt * 32 + r) * 64 + s * 8,
              &tiles[buf][1][t * 16]);
    }
    {  // V half0/half1: chunk = s*64 + r  (s = kv-slot 0..3, r = d 0..63)
      int r = t & 63, s = t >> 6;
      gload16(Vg + (size_t)r * 2048 + kvt * 32 + s * 8,
              &tiles[buf][2][t * 16]);
      gload16(Vg + (size_t)r * 2048 + 1024 + kvt * 32 + s * 8,
              &tiles[buf][3][t * 16]);
    }
  };

  f32x16 o0 = {}, o1 = {};
  float mrun = -3.0e38f, lrun = 0.f;

  stage(0, 0);
  __syncthreads();

  unsigned long long mw = ~0ull;
  bool skipm = true;

  for (int i = 0; i < 32; ++i) {
    const int cur = i & 1;
    if (i < 31) stage(cur ^ 1, i + 1);
    if ((i & 1) == 0) {
      mw = Mrow[i >> 1];
      skipm = __all(mw == ~0ull);
    }
    const int sh = (i & 1) * 32;

    const bf16x8* kb = (const bf16x8*)&tiles[cur][kvh][0];
    const bf16x8* vb = (const bf16x8*)&tiles[cur][2 + kvh][0];

    f32x16 s = {};
    {
      bf16x8 kf[4];
#pragma unroll
      for (int ck = 0; ck < 4; ck++) kf[ck] = kb[(ck * 2 + lh) * 32 + l31];
#pragma unroll
      for (int ck = 0; ck < 4; ck++) s = mfma32(kf[ck], qf[ck], s);
    }
    bf16x8 vf[4];
#pragma unroll
    for (int j = 0; j < 4; j++)
      vf[j] = vb[((j & 1) * 2 + lh) * 64 + (j >> 1) * 32 + l31];

    if (!skipm) {
      uint mh = (uint)(mw >> sh) >> lh4;
#pragma unroll
      for (int r = 0; r < 16; r++) {
        int cr = (r & 3) + 8 * (r >> 2);
        if (!((mh >> cr) & 1u)) s[r] = -1e9f;
      }
    }
    float pmax = s[0];
#pragma unroll
    for (int r = 1; r < 16; r++) pmax = fmaxf(pmax, s[r]);
    pmax = fmaxf(pmax, __shfl_xor(pmax, 32));  // cross-half max
    if (!__all(pmax <= mrun + 8.0f)) {  // defer-max (T13), wave-uniform
      float nm = fmaxf(mrun, pmax);
      float scl = __expf(mrun - nm);
      mrun = nm;
      lrun *= scl;
#pragma unroll
      for (int r = 0; r < 16; r++) {
        int cr = (r & 3) + 8 * (r >> 2);
        float sr = __shfl(scl, cr + lh4);
        o0[r] *= sr;
        o1[r] *= sr;
      }
    }
    float p[16];
    float ts = 0.f;
#pragma unroll
    for (int r = 0; r < 16; r++) {
      p[r] = __expf(s[r] - mrun);
      ts += p[r];
    }
    ts += __shfl_xor(ts, 32);  // cross-half sum
    lrun += ts;
    uint x0, x1, x2, x3, y0, y1, y2, y3;
    asm("v_cvt_pk_bf16_f32 %0, %1, %2" : "=v"(x0) : "v"(p[0]), "v"(p[1]));
    asm("v_cvt_pk_bf16_f32 %0, %1, %2" : "=v"(y0) : "v"(p[4]), "v"(p[5]));
    asm("v_cvt_pk_bf16_f32 %0, %1, %2" : "=v"(x1) : "v"(p[2]), "v"(p[3]));
    asm("v_cvt_pk_bf16_f32 %0, %1, %2" : "=v"(y1) : "v"(p[6]), "v"(p[7]));
    asm("v_cvt_pk_bf16_f32 %0, %1, %2" : "=v"(x2) : "v"(p[8]), "v"(p[9]));
    asm("v_cvt_pk_bf16_f32 %0, %1, %2" : "=v"(y2) : "v"(p[12]), "v"(p[13]));
    asm("v_cvt_pk_bf16_f32 %0, %1, %2" : "=v"(x3) : "v"(p[10]), "v"(p[11]));
    asm("v_cvt_pk_bf16_f32 %0, %1, %2" : "=v"(y3) : "v"(p[14]), "v"(p[15]));
    asm volatile("v_permlane32_swap_b32 %0, %1" : "+v"(x0), "+v"(y0));
    asm volatile("v_permlane32_swap_b32 %0, %1" : "+v"(x1), "+v"(y1));
    asm volatile("v_permlane32_swap_b32 %0, %1" : "+v"(x2), "+v"(y2));
    asm volatile("v_permlane32_swap_b32 %0, %1" : "+v"(x3), "+v"(y3));
    union { uint u[4]; bf16x8 v8; } pa0, pa1;
    pa0.u[0] = x0; pa0.u[1] = x1; pa0.u[2] = y0; pa0.u[3] = y1;
    pa1.u[0] = x2; pa1.u[1] = x3; pa1.u[2] = y2; pa1.u[3] = y3;
    o0 = mfma32(pa0.v8, vf[0], o0);
    o0 = mfma32(pa1.v8, vf[1], o0);
    o1 = mfma32(pa0.v8, vf[2], o1);
    o1 = mfma32(pa1.v8, vf[3], o1);

    __syncthreads();  // reads of buf cur done; staged tile i+1 landed
  }

  // ---- merge kv-halves (waves w and w+2 share q-sub wsb) ----
  if (lh == 0) {
    mlds[wsb][kvh][l31] = mrun;
    llds[wsb][kvh][l31] = lrun;
  }
  __syncthreads();
  float mA = mlds[wsb][0][l31], mB = mlds[wsb][1][l31];
  float lA = llds[wsb][0][l31], lB = llds[wsb][1][l31];
  float mN = fmaxf(mA, mB);
  float aA = __expf(mA - mN), aB = __expf(mB - mN);
  if (kvh) {  // high wave: scale own o, deposit to LDS (layout [reg][lane])
#pragma unroll
    for (int r = 0; r < 16; r++) {
      int cr = (r & 3) + 8 * (r >> 2);
      float ar = __shfl(aB, cr + lh4);
      olds[(wsb * 32 + r) * 64 + lane] = o0[r] * ar;
      olds[(wsb * 32 + 16 + r) * 64 + lane] = o1[r] * ar;
    }
  }
  __syncthreads();
  if (!kvh) {  // low wave: merge + epilogue
    float linv = 1.0f / (lA * aA + lB * aB);
    size_t obase = ((size_t)b * 2048 + q0) * 1024 + (size_t)h * 64 + l31;
#pragma unroll
    for (int r = 0; r < 16; r++) {
      int cr = (r & 3) + 8 * (r >> 2);
      int rho = cr + lh4;
      float ar = __shfl(aA, rho);
      float li = __shfl(linv, rho);
      float v0 = o0[r] * ar + olds[(wsb * 32 + r) * 64 + lane];
      float v1 = o1[r] * ar + olds[(wsb * 32 + 16 + r) * 64 + lane];
      ctx[obase + (size_t)rho * 1024] = __float2bfloat16(v0 * li);
      ctx[obase + (size_t)rho * 1024 + 32] = __float2bfloat16(v1 * li);
    }
  }
}

extern "C" void kernel_launch(void* const* d_in, const int* in_sizes, int n_in,
                              void* d_out, int out_size, void* d_ws,
                              size_t ws_size, hipStream_t stream) {
  const float* x = (const float*)d_in[0];
  const int* mask = (const int*)d_in[1];
  const float* Wq = (const float*)d_in[2];
  const float* bq = (const float*)d_in[3];
  const float* Wk = (const float*)d_in[4];
  const float* bk = (const float*)d_in[5];
  const float* Wv = (const float*)d_in[6];
  const float* bv = (const float*)d_in[7];
  const float* Wo = (const float*)d_in[8];
  const float* bo = (const float*)d_in[9];
  float* out = (float*)d_out;  // reference output dtype is float32
  char* ws = (char*)d_ws;

  // ws layout (bytes)
  __hip_bfloat16* xb   = (__hip_bfloat16*)(ws);              // 8 MiB
  __hip_bfloat16* wqkv = (__hip_bfloat16*)(ws + 8388608);    // 6 MiB
  __hip_bfloat16* wo   = (__hip_bfloat16*)(ws + 14680064);   // 2 MiB
  __hip_bfloat16* qws  = (__hip_bfloat16*)(ws + 16777216);   // 8 MiB
  __hip_bfloat16* kws  = (__hip_bfloat16*)(ws + 25165824);   // 8 MiB
  __hip_bfloat16* vtmp = (__hip_bfloat16*)(ws + 33554432);   // 8 MiB
  __hip_bfloat16* vt   = (__hip_bfloat16*)(ws + 41943040);   // 8 MiB
  __hip_bfloat16* ctx  = (__hip_bfloat16*)(ws + 50331648);   // 8 MiB
  unsigned long long* mbits = (unsigned long long*)(ws + 58720256);  // 1 MiB

  castf2b<<<4096, 256, 0, stream>>>(x, xb, 4194304);
  castw<<<4096, 256, 0, stream>>>(Wq, Wk, Wv, Wo, wqkv, wo);
  mask_pack<<<32768, 256, 0, stream>>>(mask, mbits);

  gemm_bt<0><<<768, 256, 0, stream>>>(xb, wqkv, bq, bk, bv, qws, kws, vtmp,
                                      nullptr, 4096, 3072, 1024);
  vtrans<<<1024, 256, 0, stream>>>(vtmp, vt);
  attn3<<<1024, 256, 0, stream>>>(qws, kws, vt, mbits, ctx);
  gemm_bt<1><<<256, 256, 0, stream>>>(ctx, wo, bo, nullptr, nullptr, nullptr,
                                      nullptr, nullptr, out, 4096, 1024, 1024);
}